// Round 1
// baseline (334.125 us; speedup 1.0000x reference)
//
#include <hip/hip_runtime.h>
#include <hip/hip_bf16.h>
#include <stdint.h>

#define B_ 4
#define S_ 2048
#define H_ 1024

typedef __attribute__((ext_vector_type(4))) float f32x4;
typedef __attribute__((ext_vector_type(8))) short bf16x8;

#define AS1C(p) ((const __attribute__((address_space(1))) void*)(p))
#define AS3(p)  ((__attribute__((address_space(3))) void*)(p))

// ---------------- fp32 -> bf16 convert ----------------
__global__ __launch_bounds__(256)
void f32_to_bf16_k(const float* __restrict__ in, __hip_bfloat16* __restrict__ out, int n4) {
    int i = blockIdx.x * blockDim.x + threadIdx.x;
    if (i < n4) {
        float4 v = ((const float4*)in)[i];
        union { __hip_bfloat16 h[4]; uint64_t u; } o;
        o.h[0] = __float2bfloat16(v.x);
        o.h[1] = __float2bfloat16(v.y);
        o.h[2] = __float2bfloat16(v.z);
        o.h[3] = __float2bfloat16(v.w);
        ((uint64_t*)out)[i] = o.u;
    }
}

// ---------------- B-transposed bf16 GEMM (m97 structure) ----------------
// C[M,N] = scale * (A[M,K] @ B[N,K]^T) + bias[N]
// 128x128 block tile, BK=32, 4 waves each computing 64x64 via 4x4 MFMA 16x16x32.
template<bool OUT_BF16, bool HAS_BIAS>
__global__ __launch_bounds__(256)
void gemm_bt(const __hip_bfloat16* __restrict__ A,
             const __hip_bfloat16* __restrict__ B,
             const float* __restrict__ bias,
             void* __restrict__ Cout,
             int M, int N, int K,
             long long aBatch, long long bBatch, long long cBatch,
             float scale)
{
    __shared__ __hip_bfloat16 lA[128 * 32];
    __shared__ __hip_bfloat16 lB[128 * 32];

    const int t  = threadIdx.x;
    const int bz = blockIdx.z;
    A += (long long)bz * aBatch;
    B += (long long)bz * bBatch;
    const int bm = blockIdx.y * 128;
    const int bn = blockIdx.x * 128;

    const int wave = t >> 6;
    const int lane = t & 63;
    const int wm = (wave & 1) * 64;
    const int wn = (wave >> 1) * 64;
    const int lm = lane & 15;   // row (A) / col (B,C) within 16
    const int kq = lane >> 4;   // k-quadrant 0..3

    f32x4 acc[4][4] = {};

    // staging: thread t loads 16B; row = t>>2 (0..63), col chunk = (t&3)*8
    const int arow = t >> 2;
    const int acol = (t & 3) * 8;
    const __hip_bfloat16* gA0 = A + (long long)(bm + arow) * K + acol;
    const __hip_bfloat16* gA1 = gA0 + (long long)64 * K;
    const __hip_bfloat16* gB0 = B + (long long)(bn + arow) * K + acol;
    const __hip_bfloat16* gB1 = gB0 + (long long)64 * K;
    __hip_bfloat16* sA0 = lA + t * 8;
    __hip_bfloat16* sA1 = lA + 2048 + t * 8;
    __hip_bfloat16* sB0 = lB + t * 8;
    __hip_bfloat16* sB1 = lB + 2048 + t * 8;

    for (int k0 = 0; k0 < K; k0 += 32) {
        __syncthreads();  // previous iteration done reading LDS
        __builtin_amdgcn_global_load_lds(AS1C(gA0 + k0), AS3(sA0), 16, 0, 0);
        __builtin_amdgcn_global_load_lds(AS1C(gA1 + k0), AS3(sA1), 16, 0, 0);
        __builtin_amdgcn_global_load_lds(AS1C(gB0 + k0), AS3(sB0), 16, 0, 0);
        __builtin_amdgcn_global_load_lds(AS1C(gB1 + k0), AS3(sB1), 16, 0, 0);
        __syncthreads();  // loads landed (vmcnt drained by barrier)

        bf16x8 af[4], bfr[4];
#pragma unroll
        for (int i = 0; i < 4; ++i) {
            af[i]  = *(const bf16x8*)(lA + (wm + i * 16 + lm) * 32 + kq * 8);
            bfr[i] = *(const bf16x8*)(lB + (wn + i * 16 + lm) * 32 + kq * 8);
        }
#pragma unroll
        for (int i = 0; i < 4; ++i)
#pragma unroll
            for (int j = 0; j < 4; ++j)
                acc[i][j] = __builtin_amdgcn_mfma_f32_16x16x32_bf16(af[i], bfr[j], acc[i][j], 0, 0, 0);
    }

    // epilogue: C/D layout col = lane&15, row = (lane>>4)*4 + reg  [m89-verified]
    const int r0 = kq * 4;
#pragma unroll
    for (int j = 0; j < 4; ++j) {
        const int col = bn + wn + j * 16 + lm;
        float bvv = 0.0f;
        if (HAS_BIAS) bvv = bias[col];
#pragma unroll
        for (int i = 0; i < 4; ++i) {
            const int rowb = bm + wm + i * 16 + r0;
#pragma unroll
            for (int r = 0; r < 4; ++r) {
                float val = acc[i][j][r] * scale + bvv;
                long long idx = (long long)bz * cBatch + (long long)(rowb + r) * N + col;
                if (OUT_BF16) ((__hip_bfloat16*)Cout)[idx] = __float2bfloat16(val);
                else          ((float*)Cout)[idx] = val;
            }
        }
    }
}

// ---------------- 64x64 LDS transpose (bf16) ----------------
// in: [rows, cols] row-major per batch; out: [cols, rows] row-major per batch.
__global__ __launch_bounds__(256)
void transpose64(const __hip_bfloat16* __restrict__ in, __hip_bfloat16* __restrict__ out,
                 int rows, int cols)
{
    __shared__ __hip_bfloat16 tile[64][66];
    long long base = (long long)blockIdx.z * rows * cols;
    in += base; out += base;
    const int c0 = blockIdx.x * 64;
    const int r0 = blockIdx.y * 64;
    const int tc  = threadIdx.x & 63;
    const int tr4 = threadIdx.x >> 6;
#pragma unroll
    for (int r = tr4; r < 64; r += 4)
        tile[r][tc] = in[(long long)(r0 + r) * cols + c0 + tc];
    __syncthreads();
#pragma unroll
    for (int r = tr4; r < 64; r += 4)
        out[(long long)(c0 + r) * rows + r0 + tc] = tile[tc][r];
}

// ---------------- row softmax over 2048 cols, in-place bf16 ----------------
__global__ __launch_bounds__(256)
void softmax_rows(__hip_bfloat16* __restrict__ s, int cols)
{
    __shared__ float red[4];
    __shared__ float red2[4];
    long long row = blockIdx.x;
    __hip_bfloat16* p = s + row * cols;
    const int t = threadIdx.x;

    float v[8];
    float mx = -1e30f;
#pragma unroll
    for (int i = 0; i < 8; ++i) {
        v[i] = __bfloat162float(p[t + i * 256]);
        mx = fmaxf(mx, v[i]);
    }
#pragma unroll
    for (int off = 32; off; off >>= 1) mx = fmaxf(mx, __shfl_down(mx, off));
    if ((t & 63) == 0) red[t >> 6] = mx;
    __syncthreads();
    mx = fmaxf(fmaxf(red[0], red[1]), fmaxf(red[2], red[3]));

    float sum = 0.0f;
#pragma unroll
    for (int i = 0; i < 8; ++i) { v[i] = __expf(v[i] - mx); sum += v[i]; }
#pragma unroll
    for (int off = 32; off; off >>= 1) sum += __shfl_down(sum, off);
    if ((t & 63) == 0) red2[t >> 6] = sum;
    __syncthreads();
    sum = red2[0] + red2[1] + red2[2] + red2[3];
    float inv = 1.0f / sum;
#pragma unroll
    for (int i = 0; i < 8; ++i) p[t + i * 256] = __float2bfloat16(v[i] * inv);
}

// ---------------- launcher ----------------
extern "C" void kernel_launch(void* const* d_in, const int* in_sizes, int n_in,
                              void* d_out, int out_size, void* d_ws, size_t ws_size,
                              hipStream_t stream)
{
    const float* X  = (const float*)d_in[0];
    const float* Wq = (const float*)d_in[1];
    const float* bq = (const float*)d_in[2];
    const float* Wk = (const float*)d_in[3];
    const float* bk = (const float*)d_in[4];
    const float* Wv = (const float*)d_in[5];
    const float* bv = (const float*)d_in[6];
    float* out = (float*)d_out;

    char* w = (char*)d_ws;
    const size_t MB = 1ull << 20;
    // Phase-1 scratch [0, 38MB): dead before scores GEMM writes sc over [0, 32MB).
    __hip_bfloat16* Xb  = (__hip_bfloat16*)(w + 0);        // 16 MB
    __hip_bfloat16* Wqb = (__hip_bfloat16*)(w + 16 * MB);  // 2 MB
    __hip_bfloat16* Wkb = (__hip_bfloat16*)(w + 18 * MB);  // 2 MB
    __hip_bfloat16* Wvb = (__hip_bfloat16*)(w + 20 * MB);  // 2 MB
    __hip_bfloat16* vb  = (__hip_bfloat16*)(w + 22 * MB);  // 16 MB (pre-transpose V)
    __hip_bfloat16* sc  = (__hip_bfloat16*)(w + 0);        // 32 MB scores/attn (reuse)
    __hip_bfloat16* qb  = (__hip_bfloat16*)(w + 40 * MB);  // 16 MB
    __hip_bfloat16* kb  = (__hip_bfloat16*)(w + 56 * MB);  // 16 MB
    __hip_bfloat16* vtb = (__hip_bfloat16*)(w + 72 * MB);  // 16 MB  (total 88 MB)

    // 1. converts
    f32_to_bf16_k<<<(B_ * S_ * H_ / 4 + 255) / 256, 256, 0, stream>>>(X, Xb, B_ * S_ * H_ / 4);
    f32_to_bf16_k<<<(H_ * H_ / 4 + 255) / 256, 256, 0, stream>>>(Wq, Wqb, H_ * H_ / 4);
    f32_to_bf16_k<<<(H_ * H_ / 4 + 255) / 256, 256, 0, stream>>>(Wk, Wkb, H_ * H_ / 4);
    f32_to_bf16_k<<<(H_ * H_ / 4 + 255) / 256, 256, 0, stream>>>(Wv, Wvb, H_ * H_ / 4);

    // 2. QKV projections: [8192,1024] = Xb @ W^T + b
    dim3 g1(H_ / 128, (B_ * S_) / 128, 1);
    gemm_bt<true, true><<<g1, 256, 0, stream>>>(Xb, Wqb, bq, qb, B_ * S_, H_, H_, 0, 0, 0, 1.0f);
    gemm_bt<true, true><<<g1, 256, 0, stream>>>(Xb, Wkb, bk, kb, B_ * S_, H_, H_, 0, 0, 0, 1.0f);
    gemm_bt<true, true><<<g1, 256, 0, stream>>>(Xb, Wvb, bv, vb, B_ * S_, H_, H_, 0, 0, 0, 1.0f);

    // 3. V -> V^T per batch: vt[b][e][s]
    transpose64<<<dim3(H_ / 64, S_ / 64, B_), 256, 0, stream>>>(vb, vtb, S_, H_);

    // 4. scores[b] = (q[b] @ k[b]^T) / 32, bf16
    dim3 g2(S_ / 128, S_ / 128, B_);
    gemm_bt<true, false><<<g2, 256, 0, stream>>>(
        qb, kb, nullptr, sc, S_, S_, H_,
        (long long)S_ * H_, (long long)S_ * H_, (long long)S_ * S_, 0.03125f);

    // 5. softmax rows (in-place)
    softmax_rows<<<B_ * S_, 256, 0, stream>>>(sc, S_);

    // 6. out[b] = attn[b] @ vt[b]^T  (fp32 out)
    dim3 g3(H_ / 128, S_ / 128, B_);
    gemm_bt<false, false><<<g3, 256, 0, stream>>>(
        sc, vtb, nullptr, out, S_, H_, S_,
        (long long)S_ * S_, (long long)H_ * S_, (long long)S_ * H_, 1.0f);
}

// Round 2
// 310.315 us; speedup vs baseline: 1.0767x; 1.0767x over previous
//
#include <hip/hip_runtime.h>
#include <hip/hip_bf16.h>
#include <stdint.h>

#define B_ 4
#define S_ 2048
#define H_ 1024

typedef __attribute__((ext_vector_type(4))) float f32x4;
typedef __attribute__((ext_vector_type(8))) short bf16x8;

#define AS1C(p) ((const __attribute__((address_space(1))) void*)(p))
#define AS3(p)  ((__attribute__((address_space(3))) void*)(p))

// ---------------- fp32 -> bf16 convert ----------------
__global__ __launch_bounds__(256)
void f32_to_bf16_k(const float* __restrict__ in, __hip_bfloat16* __restrict__ out, int n4) {
    int i = blockIdx.x * blockDim.x + threadIdx.x;
    if (i < n4) {
        float4 v = ((const float4*)in)[i];
        union { __hip_bfloat16 h[4]; uint64_t u; } o;
        o.h[0] = __float2bfloat16(v.x);
        o.h[1] = __float2bfloat16(v.y);
        o.h[2] = __float2bfloat16(v.z);
        o.h[3] = __float2bfloat16(v.w);
        ((uint64_t*)out)[i] = o.u;
    }
}

// ---------------- pack 3 bias vectors into one [3H] fp32 buffer ----------------
__global__ __launch_bounds__(256)
void pack_bias_k(const float* __restrict__ b0, const float* __restrict__ b1,
                 const float* __restrict__ b2, float* __restrict__ out) {
    int i = blockIdx.x * blockDim.x + threadIdx.x;  // 0..3071
    const float* src = (i < H_) ? b0 : (i < 2 * H_) ? b1 : b2;
    out[i] = src[i & (H_ - 1)];
}

// ---------------- B-transposed bf16 GEMM (m97 structure, ld-generalized) ------
// C[M,N] = scale * (A[M,K] @ B[N,K]^T) + bias[N]
// 128x128 block tile, BK=32, 4 waves each computing 64x64 via 4x4 MFMA 16x16x32.
template<bool OUT_BF16, bool HAS_BIAS>
__global__ __launch_bounds__(256)
void gemm_bt(const __hip_bfloat16* __restrict__ A, int lda, long long aBatch,
             const __hip_bfloat16* __restrict__ B, int ldb, long long bBatch,
             const float* __restrict__ bias,
             void* __restrict__ Cout, int ldc, long long cBatch,
             int M, int N, int K, float scale)
{
    __shared__ __hip_bfloat16 lA[128 * 32];
    __shared__ __hip_bfloat16 lB[128 * 32];

    const int t  = threadIdx.x;
    const int bz = blockIdx.z;
    A += (long long)bz * aBatch;
    B += (long long)bz * bBatch;
    const int bm = blockIdx.y * 128;
    const int bn = blockIdx.x * 128;

    const int wave = t >> 6;
    const int lane = t & 63;
    const int wm = (wave & 1) * 64;
    const int wn = (wave >> 1) * 64;
    const int lm = lane & 15;   // row (A) / col (B,C) within 16
    const int kq = lane >> 4;   // k-quadrant 0..3

    f32x4 acc[4][4] = {};

    // staging: thread t loads 16B; row = t>>2 (0..63), col chunk = (t&3)*8
    const int arow = t >> 2;
    const int acol = (t & 3) * 8;
    const __hip_bfloat16* gA0 = A + (long long)(bm + arow) * lda + acol;
    const __hip_bfloat16* gA1 = gA0 + (long long)64 * lda;
    const __hip_bfloat16* gB0 = B + (long long)(bn + arow) * ldb + acol;
    const __hip_bfloat16* gB1 = gB0 + (long long)64 * ldb;
    __hip_bfloat16* sA0 = lA + t * 8;
    __hip_bfloat16* sA1 = lA + 2048 + t * 8;
    __hip_bfloat16* sB0 = lB + t * 8;
    __hip_bfloat16* sB1 = lB + 2048 + t * 8;

    for (int k0 = 0; k0 < K; k0 += 32) {
        __syncthreads();  // previous iteration done reading LDS
        __builtin_amdgcn_global_load_lds(AS1C(gA0 + k0), AS3(sA0), 16, 0, 0);
        __builtin_amdgcn_global_load_lds(AS1C(gA1 + k0), AS3(sA1), 16, 0, 0);
        __builtin_amdgcn_global_load_lds(AS1C(gB0 + k0), AS3(sB0), 16, 0, 0);
        __builtin_amdgcn_global_load_lds(AS1C(gB1 + k0), AS3(sB1), 16, 0, 0);
        __syncthreads();  // loads landed (vmcnt drained by barrier)

        bf16x8 af[4], bfr[4];
#pragma unroll
        for (int i = 0; i < 4; ++i) {
            af[i]  = *(const bf16x8*)(lA + (wm + i * 16 + lm) * 32 + kq * 8);
            bfr[i] = *(const bf16x8*)(lB + (wn + i * 16 + lm) * 32 + kq * 8);
        }
#pragma unroll
        for (int i = 0; i < 4; ++i)
#pragma unroll
            for (int j = 0; j < 4; ++j)
                acc[i][j] = __builtin_amdgcn_mfma_f32_16x16x32_bf16(af[i], bfr[j], acc[i][j], 0, 0, 0);
    }

    // epilogue: C/D layout col = lane&15, row = (lane>>4)*4 + reg  [m89-verified]
    const int r0 = kq * 4;
#pragma unroll
    for (int j = 0; j < 4; ++j) {
        const int col = bn + wn + j * 16 + lm;
        float bvv = 0.0f;
        if (HAS_BIAS) bvv = bias[col];
#pragma unroll
        for (int i = 0; i < 4; ++i) {
            const int rowb = bm + wm + i * 16 + r0;
#pragma unroll
            for (int r = 0; r < 4; ++r) {
                float val = acc[i][j][r] * scale + bvv;
                long long idx = (long long)bz * cBatch + (long long)(rowb + r) * ldc + col;
                if (OUT_BF16) ((__hip_bfloat16*)Cout)[idx] = __float2bfloat16(val);
                else          ((float*)Cout)[idx] = val;
            }
        }
    }
}

// ---------------- 64x64 LDS transpose (bf16, strided in) ----------------
// in: [rows, cols] with leading dim ld_in; out: [cols, rows] dense per batch.
__global__ __launch_bounds__(256)
void transpose64(const __hip_bfloat16* __restrict__ in, int ld_in, long long inBatch,
                 __hip_bfloat16* __restrict__ out, long long outBatch,
                 int rows, int cols)
{
    __shared__ __hip_bfloat16 tile[64][66];
    in  += (long long)blockIdx.z * inBatch;
    out += (long long)blockIdx.z * outBatch;
    const int c0 = blockIdx.x * 64;
    const int r0 = blockIdx.y * 64;
    const int tc  = threadIdx.x & 63;
    const int tr4 = threadIdx.x >> 6;
#pragma unroll
    for (int r = tr4; r < 64; r += 4)
        tile[r][tc] = in[(long long)(r0 + r) * ld_in + c0 + tc];
    __syncthreads();
#pragma unroll
    for (int r = tr4; r < 64; r += 4)
        out[(long long)(c0 + r) * rows + r0 + tc] = tile[tc][r];
}

// ---------------- row softmax over 2048 cols, in-place bf16 ----------------
__global__ __launch_bounds__(256)
void softmax_rows(__hip_bfloat16* __restrict__ s, int cols)
{
    __shared__ float red[4];
    __shared__ float red2[4];
    long long row = blockIdx.x;
    __hip_bfloat16* p = s + row * cols;
    const int t = threadIdx.x;

    float v[8];
    float mx = -1e30f;
#pragma unroll
    for (int i = 0; i < 8; ++i) {
        v[i] = __bfloat162float(p[t + i * 256]);
        mx = fmaxf(mx, v[i]);
    }
#pragma unroll
    for (int off = 32; off; off >>= 1) mx = fmaxf(mx, __shfl_down(mx, off));
    if ((t & 63) == 0) red[t >> 6] = mx;
    __syncthreads();
    mx = fmaxf(fmaxf(red[0], red[1]), fmaxf(red[2], red[3]));

    float sum = 0.0f;
#pragma unroll
    for (int i = 0; i < 8; ++i) { v[i] = __expf(v[i] - mx); sum += v[i]; }
#pragma unroll
    for (int off = 32; off; off >>= 1) sum += __shfl_down(sum, off);
    if ((t & 63) == 0) red2[t >> 6] = sum;
    __syncthreads();
    sum = red2[0] + red2[1] + red2[2] + red2[3];
    float inv = 1.0f / sum;
#pragma unroll
    for (int i = 0; i < 8; ++i) p[t + i * 256] = __float2bfloat16(v[i] * inv);
}

// ---------------- launcher ----------------
extern "C" void kernel_launch(void* const* d_in, const int* in_sizes, int n_in,
                              void* d_out, int out_size, void* d_ws, size_t ws_size,
                              hipStream_t stream)
{
    const float* X  = (const float*)d_in[0];
    const float* Wq = (const float*)d_in[1];
    const float* bq = (const float*)d_in[2];
    const float* Wk = (const float*)d_in[3];
    const float* bk = (const float*)d_in[4];
    const float* Wv = (const float*)d_in[5];
    const float* bv = (const float*)d_in[6];
    float* out = (float*)d_out;

    char* w = (char*)d_ws;
    const size_t MB = 1ull << 20;
    // Layout (96 MB total):
    //   [0,16)   Xb        (dead after QKV gemm)
    //   [16,22)  Wall bf16 [3072,1024]   (dead after QKV gemm)
    //   [22,23)  ball fp32 [3072]        (dead after QKV gemm)
    //   [0,32)   sc  scores/attn bf16 [B,S,S]  (written step 4 — overlays dead Xb/Wall)
    //   [32,80)  qkv bf16 [8192,3072]  (q cols 0..1023, k 1024..2047, v 2048..3071)
    //   [80,96)  vtb bf16 [B,H,S]
    __hip_bfloat16* Xb   = (__hip_bfloat16*)(w + 0);
    __hip_bfloat16* Wall = (__hip_bfloat16*)(w + 16 * MB);
    float*          ball = (float*)        (w + 22 * MB);
    __hip_bfloat16* sc   = (__hip_bfloat16*)(w + 0);
    __hip_bfloat16* qkv  = (__hip_bfloat16*)(w + 32 * MB);
    __hip_bfloat16* vtb  = (__hip_bfloat16*)(w + 80 * MB);

    const int HH4 = H_ * H_ / 4;

    // 1. converts + bias pack
    f32_to_bf16_k<<<(B_ * S_ * H_ / 4 + 255) / 256, 256, 0, stream>>>(X, Xb, B_ * S_ * H_ / 4);
    f32_to_bf16_k<<<(HH4 + 255) / 256, 256, 0, stream>>>(Wq, Wall, HH4);
    f32_to_bf16_k<<<(HH4 + 255) / 256, 256, 0, stream>>>(Wk, Wall + H_ * H_, HH4);
    f32_to_bf16_k<<<(HH4 + 255) / 256, 256, 0, stream>>>(Wv, Wall + 2 * H_ * H_, HH4);
    pack_bias_k<<<(3 * H_) / 256, 256, 0, stream>>>(bq, bk, bv, ball);

    // 2. fused QKV projection: qkv[8192,3072] = Xb @ Wall^T + ball  (1536 blocks)
    dim3 g1(3 * H_ / 128, (B_ * S_) / 128, 1);
    gemm_bt<true, true><<<g1, 256, 0, stream>>>(
        Xb, H_, 0, Wall, H_, 0, ball, qkv, 3 * H_, 0, B_ * S_, 3 * H_, H_, 1.0f);

    // 3. V -> V^T per batch: vtb[b][e][s]  (V = qkv cols 2048.., row stride 3072)
    transpose64<<<dim3(H_ / 64, S_ / 64, B_), 256, 0, stream>>>(
        qkv + 2 * H_, 3 * H_, (long long)S_ * 3 * H_, vtb, (long long)H_ * S_, S_, H_);

    // 4. scores[b] = (q[b] @ k[b]^T) / 32, bf16
    dim3 g2(S_ / 128, S_ / 128, B_);
    gemm_bt<true, false><<<g2, 256, 0, stream>>>(
        qkv,      3 * H_, (long long)S_ * 3 * H_,
        qkv + H_, 3 * H_, (long long)S_ * 3 * H_,
        nullptr, sc, S_, (long long)S_ * S_, S_, S_, H_, 0.03125f);

    // 5. softmax rows (in-place)
    softmax_rows<<<B_ * S_, 256, 0, stream>>>(sc, S_);

    // 6. out[b] = attn[b] @ vtb[b]^T  (fp32 out)
    dim3 g3(H_ / 128, S_ / 128, B_);
    gemm_bt<false, false><<<g3, 256, 0, stream>>>(
        sc,  S_, (long long)S_ * S_,
        vtb, S_, (long long)H_ * S_,
        nullptr, out, H_, (long long)S_ * H_, S_, H_, S_, 1.0f);
}

// Round 3
// 271.312 us; speedup vs baseline: 1.2315x; 1.1438x over previous
//
#include <hip/hip_runtime.h>
#include <hip/hip_bf16.h>
#include <stdint.h>

#define B_ 4
#define S_ 2048
#define H_ 1024

typedef __attribute__((ext_vector_type(4))) float f32x4;
typedef __attribute__((ext_vector_type(8))) short bf16x8;

#define AS1C(p) ((const __attribute__((address_space(1))) void*)(p))
#define AS3(p)  ((__attribute__((address_space(3))) void*)(p))

// ---------------- fp32 -> bf16 convert ----------------
__global__ __launch_bounds__(256)
void f32_to_bf16_k(const float* __restrict__ in, __hip_bfloat16* __restrict__ out, int n4) {
    int i = blockIdx.x * blockDim.x + threadIdx.x;
    if (i < n4) {
        float4 v = ((const float4*)in)[i];
        union { __hip_bfloat16 h[4]; uint64_t u; } o;
        o.h[0] = __float2bfloat16(v.x);
        o.h[1] = __float2bfloat16(v.y);
        o.h[2] = __float2bfloat16(v.z);
        o.h[3] = __float2bfloat16(v.w);
        ((uint64_t*)out)[i] = o.u;
    }
}

// ---------------- pack 3 bias vectors into one [3H] fp32 buffer ----------------
__global__ __launch_bounds__(256)
void pack_bias_k(const float* __restrict__ b0, const float* __restrict__ b1,
                 const float* __restrict__ b2, float* __restrict__ out) {
    int i = blockIdx.x * blockDim.x + threadIdx.x;  // 0..3071
    const float* src = (i < H_) ? b0 : (i < 2 * H_) ? b1 : b2;
    out[i] = src[i & (H_ - 1)];
}

// ---------------- B-transposed bf16 GEMM, BK=64, XOR-swizzled staging --------
// C[M,N] = scale * (A[M,K] @ B[N,K]^T) + bias[N]
// 128x128 block tile, BK=64 (32 MFMA per barrier pair), 4 waves x 64x64 each.
// Staging swizzle: thread t fetches global 16B-chunk ((t&7)^((t>>3)&7)) of its
// row so LDS reads (row stride 128 B = all 32 banks) are 2-way max (= free).
template<bool OUT_BF16, bool HAS_BIAS>
__global__ __launch_bounds__(256)
void gemm_bt(const __hip_bfloat16* __restrict__ A, int lda, long long aBatch,
             const __hip_bfloat16* __restrict__ B, int ldb, long long bBatch,
             const float* __restrict__ bias,
             void* __restrict__ Cout, int ldc, long long cBatch,
             int M, int N, int K, float scale)
{
    __shared__ __hip_bfloat16 lA[128 * 64];   // 16 KB
    __shared__ __hip_bfloat16 lB[128 * 64];   // 16 KB -> 32 KB total, 5 blocks/CU

    const int t  = threadIdx.x;
    const int bz = blockIdx.z;
    A += (long long)bz * aBatch;
    B += (long long)bz * bBatch;
    const int bm = blockIdx.y * 128;
    const int bn = blockIdx.x * 128;

    const int wave = t >> 6;
    const int lane = t & 63;
    const int wm = (wave & 1) * 64;
    const int wn = (wave >> 1) * 64;
    const int lm = lane & 15;   // row (A) / col (B,C) within 16
    const int kq = lane >> 4;   // k-octet 0..3 within a 32-k step

    f32x4 acc[4][4] = {};

    // staging: thread t handles row (t>>3)+s*32, swizzled chunk; 4 loads per matrix
    const int srow = t >> 3;                         // 0..31
    const int swz  = ((t & 7) ^ ((t >> 3) & 7)) * 8; // global elem offset of chunk
    const __hip_bfloat16* gA = A + (long long)(bm + srow) * lda + swz;
    const __hip_bfloat16* gB = B + (long long)(bn + srow) * ldb + swz;
    __hip_bfloat16* sA = lA + t * 8;   // + s*2048 elems (wave-uniform + lane*16B)
    __hip_bfloat16* sB = lB + t * 8;

    // read side: row&7 == lm&7 for all fragment rows
    const int cro = lm & 7;

    for (int k0 = 0; k0 < K; k0 += 64) {
        __syncthreads();  // previous iteration done reading LDS
#pragma unroll
        for (int s = 0; s < 4; ++s) {
            __builtin_amdgcn_global_load_lds(AS1C(gA + (long long)s * 32 * lda + k0),
                                             AS3(sA + s * 2048), 16, 0, 0);
            __builtin_amdgcn_global_load_lds(AS1C(gB + (long long)s * 32 * ldb + k0),
                                             AS3(sB + s * 2048), 16, 0, 0);
        }
        __syncthreads();  // loads landed (vmcnt drained by barrier)

#pragma unroll
        for (int ks = 0; ks < 2; ++ks) {
            bf16x8 af[4], bfr[4];
            const int ch = ((ks * 4 + kq) ^ cro) * 8;   // swizzled LDS chunk
#pragma unroll
            for (int i = 0; i < 4; ++i) {
                af[i]  = *(const bf16x8*)(lA + (wm + i * 16 + lm) * 64 + ch);
                bfr[i] = *(const bf16x8*)(lB + (wn + i * 16 + lm) * 64 + ch);
            }
#pragma unroll
            for (int i = 0; i < 4; ++i)
#pragma unroll
                for (int j = 0; j < 4; ++j)
                    acc[i][j] = __builtin_amdgcn_mfma_f32_16x16x32_bf16(af[i], bfr[j], acc[i][j], 0, 0, 0);
        }
    }

    // epilogue: C/D layout col = lane&15, row = (lane>>4)*4 + reg  [m89-verified]
    const int r0 = kq * 4;
#pragma unroll
    for (int j = 0; j < 4; ++j) {
        const int col = bn + wn + j * 16 + lm;
        float bvv = 0.0f;
        if (HAS_BIAS) bvv = bias[col];
#pragma unroll
        for (int i = 0; i < 4; ++i) {
            const int rowb = bm + wm + i * 16 + r0;
#pragma unroll
            for (int r = 0; r < 4; ++r) {
                float val = acc[i][j][r] * scale + bvv;
                long long idx = (long long)bz * cBatch + (long long)(rowb + r) * ldc + col;
                if (OUT_BF16) ((__hip_bfloat16*)Cout)[idx] = __float2bfloat16(val);
                else          ((float*)Cout)[idx] = val;
            }
        }
    }
}

// ---------------- 64x64 LDS transpose (bf16, strided in) ----------------
__global__ __launch_bounds__(256)
void transpose64(const __hip_bfloat16* __restrict__ in, int ld_in, long long inBatch,
                 __hip_bfloat16* __restrict__ out, long long outBatch,
                 int rows, int cols)
{
    __shared__ __hip_bfloat16 tile[64][66];
    in  += (long long)blockIdx.z * inBatch;
    out += (long long)blockIdx.z * outBatch;
    const int c0 = blockIdx.x * 64;
    const int r0 = blockIdx.y * 64;
    const int tc  = threadIdx.x & 63;
    const int tr4 = threadIdx.x >> 6;
#pragma unroll
    for (int r = tr4; r < 64; r += 4)
        tile[r][tc] = in[(long long)(r0 + r) * ld_in + c0 + tc];
    __syncthreads();
#pragma unroll
    for (int r = tr4; r < 64; r += 4)
        out[(long long)(c0 + r) * rows + r0 + tc] = tile[tc][r];
}

// ---------------- row softmax over 2048 cols, in-place bf16, 16B/lane --------
__global__ __launch_bounds__(256)
void softmax_rows(__hip_bfloat16* __restrict__ s, int cols)
{
    __shared__ float red[4];
    __shared__ float red2[4];
    __hip_bfloat16* p = s + (long long)blockIdx.x * cols;
    const int t = threadIdx.x;

    union { uint4 u; __hip_bfloat16 h[8]; } in;
    in.u = *(const uint4*)(p + t * 8);
    float v[8];
    float mx = -1e30f;
#pragma unroll
    for (int i = 0; i < 8; ++i) {
        v[i] = __bfloat162float(in.h[i]);
        mx = fmaxf(mx, v[i]);
    }
#pragma unroll
    for (int off = 32; off; off >>= 1) mx = fmaxf(mx, __shfl_down(mx, off));
    if ((t & 63) == 0) red[t >> 6] = mx;
    __syncthreads();
    mx = fmaxf(fmaxf(red[0], red[1]), fmaxf(red[2], red[3]));

    float sum = 0.0f;
#pragma unroll
    for (int i = 0; i < 8; ++i) { v[i] = __expf(v[i] - mx); sum += v[i]; }
#pragma unroll
    for (int off = 32; off; off >>= 1) sum += __shfl_down(sum, off);
    if ((t & 63) == 0) red2[t >> 6] = sum;
    __syncthreads();
    sum = red2[0] + red2[1] + red2[2] + red2[3];
    float inv = 1.0f / sum;
    union { uint4 u; __hip_bfloat16 h[8]; } o;
#pragma unroll
    for (int i = 0; i < 8; ++i) o.h[i] = __float2bfloat16(v[i] * inv);
    *(uint4*)(p + t * 8) = o.u;
}

// ---------------- launcher ----------------
extern "C" void kernel_launch(void* const* d_in, const int* in_sizes, int n_in,
                              void* d_out, int out_size, void* d_ws, size_t ws_size,
                              hipStream_t stream)
{
    const float* X  = (const float*)d_in[0];
    const float* Wq = (const float*)d_in[1];
    const float* bq = (const float*)d_in[2];
    const float* Wk = (const float*)d_in[3];
    const float* bk = (const float*)d_in[4];
    const float* Wv = (const float*)d_in[5];
    const float* bv = (const float*)d_in[6];
    float* out = (float*)d_out;

    char* w = (char*)d_ws;
    const size_t MB = 1ull << 20;
    // Layout (96 MB total):
    //   [0,16)   Xb        (dead after QKV gemm)
    //   [16,22)  Wall bf16 [3072,1024]   (dead after QKV gemm)
    //   [22,23)  ball fp32 [3072]        (dead after QKV gemm)
    //   [0,32)   sc  scores/attn bf16 [B,S,S]  (written step 4 — overlays dead Xb/Wall)
    //   [32,80)  qkv bf16 [8192,3072]  (q cols 0..1023, k 1024..2047, v 2048..3071)
    //   [80,96)  vtb bf16 [B,H,S]
    __hip_bfloat16* Xb   = (__hip_bfloat16*)(w + 0);
    __hip_bfloat16* Wall = (__hip_bfloat16*)(w + 16 * MB);
    float*          ball = (float*)        (w + 22 * MB);
    __hip_bfloat16* sc   = (__hip_bfloat16*)(w + 0);
    __hip_bfloat16* qkv  = (__hip_bfloat16*)(w + 32 * MB);
    __hip_bfloat16* vtb  = (__hip_bfloat16*)(w + 80 * MB);

    const int HH4 = H_ * H_ / 4;

    // 1. converts + bias pack
    f32_to_bf16_k<<<(B_ * S_ * H_ / 4 + 255) / 256, 256, 0, stream>>>(X, Xb, B_ * S_ * H_ / 4);
    f32_to_bf16_k<<<(HH4 + 255) / 256, 256, 0, stream>>>(Wq, Wall, HH4);
    f32_to_bf16_k<<<(HH4 + 255) / 256, 256, 0, stream>>>(Wk, Wall + H_ * H_, HH4);
    f32_to_bf16_k<<<(HH4 + 255) / 256, 256, 0, stream>>>(Wv, Wall + 2 * H_ * H_, HH4);
    pack_bias_k<<<(3 * H_) / 256, 256, 0, stream>>>(bq, bk, bv, ball);

    // 2. fused QKV projection: qkv[8192,3072] = Xb @ Wall^T + ball  (1536 blocks)
    dim3 g1(3 * H_ / 128, (B_ * S_) / 128, 1);
    gemm_bt<true, true><<<g1, 256, 0, stream>>>(
        Xb, H_, 0, Wall, H_, 0, ball, qkv, 3 * H_, 0, B_ * S_, 3 * H_, H_, 1.0f);

    // 3. V -> V^T per batch: vtb[b][e][s]  (V = qkv cols 2048.., row stride 3072)
    transpose64<<<dim3(H_ / 64, S_ / 64, B_), 256, 0, stream>>>(
        qkv + 2 * H_, 3 * H_, (long long)S_ * 3 * H_, vtb, (long long)H_ * S_, S_, H_);

    // 4. scores[b] = (q[b] @ k[b]^T) / 32, bf16
    dim3 g2(S_ / 128, S_ / 128, B_);
    gemm_bt<true, false><<<g2, 256, 0, stream>>>(
        qkv,      3 * H_, (long long)S_ * 3 * H_,
        qkv + H_, 3 * H_, (long long)S_ * 3 * H_,
        nullptr, sc, S_, (long long)S_ * S_, S_, S_, H_, 0.03125f);

    // 5. softmax rows (in-place)
    softmax_rows<<<B_ * S_, 256, 0, stream>>>(sc, S_);

    // 6. out[b] = attn[b] @ vtb[b]^T  (fp32 out)
    dim3 g3(H_ / 128, S_ / 128, B_);
    gemm_bt<false, false><<<g3, 256, 0, stream>>>(
        sc,  S_, (long long)S_ * S_,
        vtb, S_, (long long)H_ * S_,
        nullptr, out, H_, (long long)S_ * H_, S_, H_, S_, 1.0f);
}

// Round 4
// 268.181 us; speedup vs baseline: 1.2459x; 1.0117x over previous
//
#include <hip/hip_runtime.h>
#include <hip/hip_bf16.h>
#include <stdint.h>

#define B_ 4
#define S_ 2048
#define H_ 1024

typedef __attribute__((ext_vector_type(16))) float f32x16;
typedef __attribute__((ext_vector_type(8))) short bf16x8;

#define AS1C(p) ((const __attribute__((address_space(1))) void*)(p))
#define AS3(p)  ((__attribute__((address_space(3))) void*)(p))

// ---------------- fp32 -> bf16 convert (X) ----------------
__global__ __launch_bounds__(256)
void f32_to_bf16_k(const float* __restrict__ in, __hip_bfloat16* __restrict__ out, int n4) {
    int i = blockIdx.x * blockDim.x + threadIdx.x;
    if (i < n4) {
        float4 v = ((const float4*)in)[i];
        union { __hip_bfloat16 h[4]; uint64_t u; } o;
        o.h[0] = __float2bfloat16(v.x);
        o.h[1] = __float2bfloat16(v.y);
        o.h[2] = __float2bfloat16(v.z);
        o.h[3] = __float2bfloat16(v.w);
        ((uint64_t*)out)[i] = o.u;
    }
}

// ---------------- convert 3 weight matrices in one launch ----------------
__global__ __launch_bounds__(256)
void conv_weights_k(const float* __restrict__ w0, const float* __restrict__ w1,
                    const float* __restrict__ w2, __hip_bfloat16* __restrict__ out) {
    const int per = H_ * H_ / 4;
    int i = blockIdx.x * blockDim.x + threadIdx.x;  // 0 .. 3*per-1
    const float* src = (i < per) ? w0 : (i < 2 * per) ? w1 : w2;
    int li = i - ((i < per) ? 0 : (i < 2 * per) ? per : 2 * per);
    float4 v = ((const float4*)src)[li];
    union { __hip_bfloat16 h[4]; uint64_t u; } o;
    o.h[0] = __float2bfloat16(v.x);
    o.h[1] = __float2bfloat16(v.y);
    o.h[2] = __float2bfloat16(v.z);
    o.h[3] = __float2bfloat16(v.w);
    ((uint64_t*)out)[i] = o.u;
}

// ---------------- pack 3 bias vectors into one [3H] fp32 buffer ----------------
__global__ __launch_bounds__(256)
void pack_bias_k(const float* __restrict__ b0, const float* __restrict__ b1,
                 const float* __restrict__ b2, float* __restrict__ out) {
    int i = blockIdx.x * blockDim.x + threadIdx.x;  // 0..3071
    const float* src = (i < H_) ? b0 : (i < 2 * H_) ? b1 : b2;
    out[i] = src[i & (H_ - 1)];
}

// ---------------- B-transposed bf16 GEMM, 32x32x16 MFMA, BK=64, swizzled -----
// C[M,N] = scale * (A[M,K] @ B[N,K]^T) + bias[N]
// 128x128 block tile, 4 waves x 64x64 each as 2x2 of 32x32x16 MFMA.
// V_SPLIT: blocks with bn>=2048 write transposed into vtrans[b][e][s] instead.
template<bool OUT_BF16, bool HAS_BIAS, bool V_SPLIT>
__global__ __launch_bounds__(256)
void gemm_bt(const __hip_bfloat16* __restrict__ A, int lda, long long aBatch,
             const __hip_bfloat16* __restrict__ B, int ldb, long long bBatch,
             const float* __restrict__ bias,
             void* __restrict__ Cout, int ldc, long long cBatch,
             __hip_bfloat16* __restrict__ vtrans,
             int M, int N, int K, float scale)
{
    __shared__ __hip_bfloat16 lA[128 * 64];   // 16 KB
    __shared__ __hip_bfloat16 lB[128 * 64];   // 16 KB

    const int t  = threadIdx.x;
    const int bz = blockIdx.z;
    A += (long long)bz * aBatch;
    B += (long long)bz * bBatch;
    const int bm = blockIdx.y * 128;
    const int bn = blockIdx.x * 128;

    const int wave = t >> 6;
    const int lane = t & 63;
    const int wm = (wave & 1) * 64;
    const int wn = (wave >> 1) * 64;
    const int lr = lane & 31;   // row (A) / col (B,C) within 32
    const int kh = lane >> 5;   // k-half 0..1

    f32x16 acc[2][2] = {};

    // staging: thread t handles row (t>>3)+s*32, swizzled chunk; 4 loads per matrix.
    // Global chunk c of row r lands at LDS chunk position c^(r&7).
    const int srow = t >> 3;                         // 0..31
    const int swz  = ((t & 7) ^ ((t >> 3) & 7)) * 8; // global elem offset of chunk
    const __hip_bfloat16* gA = A + (long long)(bm + srow) * lda + swz;
    const __hip_bfloat16* gB = B + (long long)(bn + srow) * ldb + swz;
    __hip_bfloat16* sA = lA + t * 8;   // wave-uniform base + lane*16B
    __hip_bfloat16* sB = lB + t * 8;

    for (int k0 = 0; k0 < K; k0 += 64) {
        __syncthreads();  // previous iteration done reading LDS
#pragma unroll
        for (int s = 0; s < 4; ++s) {
            __builtin_amdgcn_global_load_lds(AS1C(gA + (long long)s * 32 * lda + k0),
                                             AS3(sA + s * 2048), 16, 0, 0);
            __builtin_amdgcn_global_load_lds(AS1C(gB + (long long)s * 32 * ldb + k0),
                                             AS3(sB + s * 2048), 16, 0, 0);
        }
        __syncthreads();  // loads landed

#pragma unroll
        for (int ks = 0; ks < 4; ++ks) {            // K=16 per step
            bf16x8 af[2], bfr[2];
            const int ch = ((ks * 2 + kh) ^ (lane & 7)) * 8;  // swizzled LDS chunk
#pragma unroll
            for (int i = 0; i < 2; ++i) {
                af[i]  = *(const bf16x8*)(lA + (wm + i * 32 + lr) * 64 + ch);
                bfr[i] = *(const bf16x8*)(lB + (wn + i * 32 + lr) * 64 + ch);
            }
#pragma unroll
            for (int i = 0; i < 2; ++i)
#pragma unroll
                for (int j = 0; j < 2; ++j)
                    acc[i][j] = __builtin_amdgcn_mfma_f32_32x32x16_bf16(af[i], bfr[j], acc[i][j], 0, 0, 0);
        }
    }

    // epilogue: 32x32 C/D layout col = lane&31, row = (reg&3) + 8*(reg>>2) + 4*(lane>>5)
    const bool vmode = V_SPLIT && (bn >= 2 * H_);
#pragma unroll
    for (int j = 0; j < 2; ++j) {
        const int col = bn + wn + j * 32 + lr;
        float bvv = 0.0f;
        if (HAS_BIAS) bvv = bias[col];
#pragma unroll
        for (int i = 0; i < 2; ++i) {
            const int rowb = bm + wm + i * 32 + 4 * kh;
            if (!vmode) {
#pragma unroll
                for (int g = 0; g < 4; ++g)
#pragma unroll
                    for (int r = 0; r < 4; ++r) {
                        float val = acc[i][j][g * 4 + r] * scale + bvv;
                        long long idx = (long long)bz * cBatch + (long long)(rowb + g * 8 + r) * ldc + col;
                        if (OUT_BF16) ((__hip_bfloat16*)Cout)[idx] = __float2bfloat16(val);
                        else          ((float*)Cout)[idx] = val;
                    }
            } else {
                // vtrans[b][e][s]: b = rowb>>11, s = rowb&2047, e = col - 2048
                const long long ebase = (long long)((rowb >> 11) * H_ + col - 2 * H_) * S_;
                const int s0 = rowb & 2047;
#pragma unroll
                for (int g = 0; g < 4; ++g) {
                    union { ushort4 u; __hip_bfloat16 h[4]; } o;
#pragma unroll
                    for (int r = 0; r < 4; ++r)
                        o.h[r] = __float2bfloat16(acc[i][j][g * 4 + r] * scale + bvv);
                    *(ushort4*)(vtrans + ebase + s0 + g * 8) = o.u;
                }
            }
        }
    }
}

// ---------------- row softmax over 2048 cols, in-place bf16, 16B/lane --------
__global__ __launch_bounds__(256)
void softmax_rows(__hip_bfloat16* __restrict__ s, int cols)
{
    __shared__ float red[4];
    __shared__ float red2[4];
    __hip_bfloat16* p = s + (long long)blockIdx.x * cols;
    const int t = threadIdx.x;

    union { uint4 u; __hip_bfloat16 h[8]; } in;
    in.u = *(const uint4*)(p + t * 8);
    float v[8];
    float mx = -1e30f;
#pragma unroll
    for (int i = 0; i < 8; ++i) {
        v[i] = __bfloat162float(in.h[i]);
        mx = fmaxf(mx, v[i]);
    }
#pragma unroll
    for (int off = 32; off; off >>= 1) mx = fmaxf(mx, __shfl_down(mx, off));
    if ((t & 63) == 0) red[t >> 6] = mx;
    __syncthreads();
    mx = fmaxf(fmaxf(red[0], red[1]), fmaxf(red[2], red[3]));

    float sum = 0.0f;
#pragma unroll
    for (int i = 0; i < 8; ++i) { v[i] = __expf(v[i] - mx); sum += v[i]; }
#pragma unroll
    for (int off = 32; off; off >>= 1) sum += __shfl_down(sum, off);
    if ((t & 63) == 0) red2[t >> 6] = sum;
    __syncthreads();
    sum = red2[0] + red2[1] + red2[2] + red2[3];
    float inv = 1.0f / sum;
    union { uint4 u; __hip_bfloat16 h[8]; } o;
#pragma unroll
    for (int i = 0; i < 8; ++i) o.h[i] = __float2bfloat16(v[i] * inv);
    *(uint4*)(p + t * 8) = o.u;
}

// ---------------- launcher ----------------
extern "C" void kernel_launch(void* const* d_in, const int* in_sizes, int n_in,
                              void* d_out, int out_size, void* d_ws, size_t ws_size,
                              hipStream_t stream)
{
    const float* X  = (const float*)d_in[0];
    const float* Wq = (const float*)d_in[1];
    const float* bq = (const float*)d_in[2];
    const float* Wk = (const float*)d_in[3];
    const float* bk = (const float*)d_in[4];
    const float* Wv = (const float*)d_in[5];
    const float* bv = (const float*)d_in[6];
    float* out = (float*)d_out;

    char* w = (char*)d_ws;
    const size_t MB = 1ull << 20;
    // Layout (96 MB total):
    //   [0,16)   Xb        (dead after QKV gemm)
    //   [16,22)  Wall bf16 [3072,1024]   (dead after QKV gemm)
    //   [22,23)  ball fp32 [3072]        (dead after QKV gemm)
    //   [0,32)   sc  scores/attn bf16 [B,S,S]  (overlays dead Xb/Wall)
    //   [32,80)  qkv bf16 [8192,3072]  (Q cols 0..1023, K 1024..2047; V region unused)
    //   [80,96)  vtb bf16 [B,H,S]  (written transposed by QKV gemm epilogue)
    __hip_bfloat16* Xb   = (__hip_bfloat16*)(w + 0);
    __hip_bfloat16* Wall = (__hip_bfloat16*)(w + 16 * MB);
    float*          ball = (float*)        (w + 22 * MB);
    __hip_bfloat16* sc   = (__hip_bfloat16*)(w + 0);
    __hip_bfloat16* qkv  = (__hip_bfloat16*)(w + 32 * MB);
    __hip_bfloat16* vtb  = (__hip_bfloat16*)(w + 80 * MB);

    // 1. converts + bias pack
    f32_to_bf16_k<<<(B_ * S_ * H_ / 4 + 255) / 256, 256, 0, stream>>>(X, Xb, B_ * S_ * H_ / 4);
    conv_weights_k<<<(3 * H_ * H_ / 4 + 255) / 256, 256, 0, stream>>>(Wq, Wk, Wv, Wall);
    pack_bias_k<<<(3 * H_) / 256, 256, 0, stream>>>(bq, bk, bv, ball);

    // 2. fused QKV projection; V blocks (bx>=16) write transposed to vtb
    dim3 g1(3 * H_ / 128, (B_ * S_) / 128, 1);
    gemm_bt<true, true, true><<<g1, 256, 0, stream>>>(
        Xb, H_, 0, Wall, H_, 0, ball, qkv, 3 * H_, 0, vtb, B_ * S_, 3 * H_, H_, 1.0f);

    // 3. scores[b] = (q[b] @ k[b]^T) / 32, bf16
    dim3 g2(S_ / 128, S_ / 128, B_);
    gemm_bt<true, false, false><<<g2, 256, 0, stream>>>(
        qkv,      3 * H_, (long long)S_ * 3 * H_,
        qkv + H_, 3 * H_, (long long)S_ * 3 * H_,
        nullptr, sc, S_, (long long)S_ * S_, nullptr, S_, S_, H_, 0.03125f);

    // 4. softmax rows (in-place)
    softmax_rows<<<B_ * S_, 256, 0, stream>>>(sc, S_);

    // 5. out[b] = attn[b] @ vtb[b]^T  (fp32 out)
    dim3 g3(H_ / 128, S_ / 128, B_);
    gemm_bt<false, false, false><<<g3, 256, 0, stream>>>(
        sc,  S_, (long long)S_ * S_,
        vtb, S_, (long long)H_ * S_,
        nullptr, out, H_, (long long)S_ * H_, nullptr, S_, H_, S_, 1.0f);
}

// Round 5
// 263.665 us; speedup vs baseline: 1.2672x; 1.0171x over previous
//
#include <hip/hip_runtime.h>
#include <hip/hip_bf16.h>
#include <stdint.h>

#define B_ 4
#define S_ 2048
#define H_ 1024

typedef __attribute__((ext_vector_type(4))) float f32x4;
typedef __attribute__((ext_vector_type(8))) short bf16x8;

#define AS1C(p) ((const __attribute__((address_space(1))) void*)(p))
#define AS3(p)  ((__attribute__((address_space(3))) void*)(p))

// ---------------- one-shot prep: convert X, Wq|Wk|Wv, pack biases ----------------
__global__ __launch_bounds__(256)
void prep_k(const float* __restrict__ X,
            const float* __restrict__ Wq, const float* __restrict__ Wk,
            const float* __restrict__ Wv,
            const float* __restrict__ bq, const float* __restrict__ bk,
            const float* __restrict__ bv,
            __hip_bfloat16* __restrict__ Xb, __hip_bfloat16* __restrict__ Wall,
            float* __restrict__ ball)
{
    const int NX = B_ * S_ * H_ / 4;   // float4 count of X
    const int NW = H_ * H_ / 4;        // float4 count of one W
    int i = blockIdx.x * blockDim.x + threadIdx.x;
    if (i < NX + 3 * NW) {
        const float* src; uint64_t* dst; int li;
        if (i < NX) { src = X; dst = (uint64_t*)Xb; li = i; }
        else {
            int j = i - NX;
            int wsel = j / NW; li = j - wsel * NW;
            src = (wsel == 0) ? Wq : (wsel == 1) ? Wk : Wv;
            dst = (uint64_t*)Wall + (size_t)wsel * NW;
        }
        float4 v = ((const float4*)src)[li];
        union { __hip_bfloat16 h[4]; uint64_t u; } o;
        o.h[0] = __float2bfloat16(v.x);
        o.h[1] = __float2bfloat16(v.y);
        o.h[2] = __float2bfloat16(v.z);
        o.h[3] = __float2bfloat16(v.w);
        dst[li] = o.u;
    } else {
        int j = i - (NX + 3 * NW);     // 0..767 float4 of bias
        if (j < 3 * H_ / 4) {
            int bsel = j >> 8;          // 256 float4 per bias
            int off  = j & 255;
            const float* src = (bsel == 0) ? bq : (bsel == 1) ? bk : bv;
            ((float4*)ball)[j] = ((const float4*)src)[off];
        }
    }
}

// ---------------- B-transposed bf16 GEMM, 16x16x32 MFMA, BK=64, dbuf pipeline ----
// C[M,N] = scale * (A[M,K] @ B[N,K]^T) + bias[N]
// 128x128 block tile, 4 waves x 64x64 (4x4 of 16x16x32).
// K-loop: 2-buffer LDS, stage(it+1) issued BEFORE waiting on stage(it);
// raw "s_waitcnt vmcnt(8); s_barrier" keeps the prefetch in flight (never vmcnt(0)).
// XOR chunk swizzle (proven 0-conflict in this read pattern, r3).
// V_SPLIT: blocks with bn>=2048 write transposed into vtrans[b][e][s].
template<bool OUT_BF16, bool HAS_BIAS, bool V_SPLIT>
__global__ __launch_bounds__(256)
void gemm_bt(const __hip_bfloat16* __restrict__ A, int lda, long long aBatch,
             const __hip_bfloat16* __restrict__ B, int ldb, long long bBatch,
             const float* __restrict__ bias,
             void* __restrict__ Cout, int ldc, long long cBatch,
             __hip_bfloat16* __restrict__ vtrans,
             int M, int N, int K, float scale)
{
    __shared__ __hip_bfloat16 lA[2][128 * 64];   // 2 x 16 KB
    __shared__ __hip_bfloat16 lB[2][128 * 64];   // 2 x 16 KB  -> 64 KB total

    const int t  = threadIdx.x;
    const int bz = blockIdx.z;
    A += (long long)bz * aBatch;
    B += (long long)bz * bBatch;
    const int bm = blockIdx.y * 128;
    const int bn = blockIdx.x * 128;

    const int wave = t >> 6;
    const int lane = t & 63;
    const int wm = (wave & 1) * 64;
    const int wn = (wave >> 1) * 64;
    const int lm = lane & 15;   // row (A) / col (B,C) within 16
    const int kq = lane >> 4;   // k-quadrant 0..3
    const int cro = lm & 7;     // read-side swizzle key

    f32x4 acc[4][4] = {};

    // staging: thread t handles row (t>>3)+s*32, swizzled chunk (t&7)^((t>>3)&7)
    const int srow = t >> 3;
    const int swz  = ((t & 7) ^ ((t >> 3) & 7)) * 8;
    const __hip_bfloat16* gA = A + (long long)(bm + srow) * lda + swz;
    const __hip_bfloat16* gB = B + (long long)(bn + srow) * ldb + swz;

    const int NIT = K >> 6;

#define STAGE(buf, kk)                                                              \
    {                                                                               \
        __hip_bfloat16* sA = &lA[buf][0] + t * 8;                                   \
        __hip_bfloat16* sB = &lB[buf][0] + t * 8;                                   \
        _Pragma("unroll")                                                           \
        for (int s = 0; s < 4; ++s) {                                               \
            __builtin_amdgcn_global_load_lds(AS1C(gA + (long long)s * 32 * lda + (kk)), \
                                             AS3(sA + s * 2048), 16, 0, 0);         \
            __builtin_amdgcn_global_load_lds(AS1C(gB + (long long)s * 32 * ldb + (kk)), \
                                             AS3(sB + s * 2048), 16, 0, 0);         \
        }                                                                           \
    }

    STAGE(0, 0);

    for (int it = 0; it < NIT; ++it) {
        const int cur = it & 1;
        if (it + 1 < NIT) {
            STAGE(cur ^ 1, (it + 1) << 6);
            asm volatile("s_waitcnt vmcnt(8)\n\ts_barrier" ::: "memory");
        } else {
            asm volatile("s_waitcnt vmcnt(0)\n\ts_barrier" ::: "memory");
        }

#pragma unroll
        for (int ks = 0; ks < 2; ++ks) {
            bf16x8 af[4], bfr[4];
            const int ch = ((ks * 4 + kq) ^ cro) * 8;
#pragma unroll
            for (int i = 0; i < 4; ++i) {
                af[i]  = *(const bf16x8*)(&lA[cur][0] + (wm + i * 16 + lm) * 64 + ch);
                bfr[i] = *(const bf16x8*)(&lB[cur][0] + (wn + i * 16 + lm) * 64 + ch);
            }
#pragma unroll
            for (int i = 0; i < 4; ++i)
#pragma unroll
                for (int j = 0; j < 4; ++j)
                    acc[i][j] = __builtin_amdgcn_mfma_f32_16x16x32_bf16(af[i], bfr[j], acc[i][j], 0, 0, 0);
        }

        if (it + 1 < NIT)
            asm volatile("s_barrier" ::: "memory");   // all done reading buf[cur] before restage
    }
#undef STAGE

    // epilogue: 16x16 C/D layout col = lane&15, row = (lane>>4)*4 + reg  [m89]
    const bool vmode = V_SPLIT && (bn >= 2 * H_);
    const int r0q = kq * 4;
#pragma unroll
    for (int j = 0; j < 4; ++j) {
        const int col = bn + wn + j * 16 + lm;
        float bvv = 0.0f;
        if (HAS_BIAS) bvv = bias[col];
#pragma unroll
        for (int i = 0; i < 4; ++i) {
            const int rowb = bm + wm + i * 16 + r0q;
            if (!vmode) {
#pragma unroll
                for (int r = 0; r < 4; ++r) {
                    float val = acc[i][j][r] * scale + bvv;
                    long long idx = (long long)bz * cBatch + (long long)(rowb + r) * ldc + col;
                    if (OUT_BF16) ((__hip_bfloat16*)Cout)[idx] = __float2bfloat16(val);
                    else          ((float*)Cout)[idx] = val;
                }
            } else {
                // vtrans[b][e][s]: b = rowb>>11, s = rowb&2047 (+r contiguous), e = col-2048
                const long long ebase = (long long)((rowb >> 11) * H_ + col - 2 * H_) * S_;
                union { ushort4 u; __hip_bfloat16 h[4]; } o;
#pragma unroll
                for (int r = 0; r < 4; ++r)
                    o.h[r] = __float2bfloat16(acc[i][j][r] * scale + bvv);
                *(ushort4*)(vtrans + ebase + (rowb & 2047)) = o.u;
            }
        }
    }
}

// ---------------- row softmax over 2048 cols, in-place bf16, 16B/lane --------
__global__ __launch_bounds__(256)
void softmax_rows(__hip_bfloat16* __restrict__ s, int cols)
{
    __shared__ float red[4];
    __shared__ float red2[4];
    __hip_bfloat16* p = s + (long long)blockIdx.x * cols;
    const int t = threadIdx.x;

    union { uint4 u; __hip_bfloat16 h[8]; } in;
    in.u = *(const uint4*)(p + t * 8);
    float v[8];
    float mx = -1e30f;
#pragma unroll
    for (int i = 0; i < 8; ++i) {
        v[i] = __bfloat162float(in.h[i]);
        mx = fmaxf(mx, v[i]);
    }
#pragma unroll
    for (int off = 32; off; off >>= 1) mx = fmaxf(mx, __shfl_down(mx, off));
    if ((t & 63) == 0) red[t >> 6] = mx;
    __syncthreads();
    mx = fmaxf(fmaxf(red[0], red[1]), fmaxf(red[2], red[3]));

    float sum = 0.0f;
#pragma unroll
    for (int i = 0; i < 8; ++i) { v[i] = __expf(v[i] - mx); sum += v[i]; }
#pragma unroll
    for (int off = 32; off; off >>= 1) sum += __shfl_down(sum, off);
    if ((t & 63) == 0) red2[t >> 6] = sum;
    __syncthreads();
    sum = red2[0] + red2[1] + red2[2] + red2[3];
    float inv = 1.0f / sum;
    union { uint4 u; __hip_bfloat16 h[8]; } o;
#pragma unroll
    for (int i = 0; i < 8; ++i) o.h[i] = __float2bfloat16(v[i] * inv);
    *(uint4*)(p + t * 8) = o.u;
}

// ---------------- launcher ----------------
extern "C" void kernel_launch(void* const* d_in, const int* in_sizes, int n_in,
                              void* d_out, int out_size, void* d_ws, size_t ws_size,
                              hipStream_t stream)
{
    const float* X  = (const float*)d_in[0];
    const float* Wq = (const float*)d_in[1];
    const float* bq = (const float*)d_in[2];
    const float* Wk = (const float*)d_in[3];
    const float* bk = (const float*)d_in[4];
    const float* Wv = (const float*)d_in[5];
    const float* bv = (const float*)d_in[6];
    float* out = (float*)d_out;

    char* w = (char*)d_ws;
    const size_t MB = 1ull << 20;
    // Layout (96 MB total):
    //   [0,16)   Xb        (dead after QKV gemm)
    //   [16,22)  Wall bf16 [3072,1024]   (dead after QKV gemm)
    //   [22,23)  ball fp32 [3072]        (dead after QKV gemm)
    //   [0,32)   sc  scores/attn bf16 [B,S,S]  (overlays dead Xb/Wall)
    //   [32,80)  qkv bf16 [8192,3072]  (Q cols 0..1023, K 1024..2047; V third unused)
    //   [80,96)  vtb bf16 [B,H,S]  (written transposed by QKV gemm epilogue)
    __hip_bfloat16* Xb   = (__hip_bfloat16*)(w + 0);
    __hip_bfloat16* Wall = (__hip_bfloat16*)(w + 16 * MB);
    float*          ball = (float*)        (w + 22 * MB);
    __hip_bfloat16* sc   = (__hip_bfloat16*)(w + 0);
    __hip_bfloat16* qkv  = (__hip_bfloat16*)(w + 32 * MB);
    __hip_bfloat16* vtb  = (__hip_bfloat16*)(w + 80 * MB);

    // 1. single prep launch (X convert + W convert + bias pack)
    const int prep_items = B_ * S_ * H_ / 4 + 3 * H_ * H_ / 4 + 3 * H_ / 4;
    prep_k<<<(prep_items + 255) / 256, 256, 0, stream>>>(X, Wq, Wk, Wv, bq, bk, bv,
                                                         Xb, Wall, ball);

    // 2. fused QKV projection; V blocks (bx>=16) write transposed to vtb
    dim3 g1(3 * H_ / 128, (B_ * S_) / 128, 1);
    gemm_bt<true, true, true><<<g1, 256, 0, stream>>>(
        Xb, H_, 0, Wall, H_, 0, ball, qkv, 3 * H_, 0, vtb, B_ * S_, 3 * H_, H_, 1.0f);

    // 3. scores[b] = (q[b] @ k[b]^T) / 32, bf16
    dim3 g2(S_ / 128, S_ / 128, B_);
    gemm_bt<true, false, false><<<g2, 256, 0, stream>>>(
        qkv,      3 * H_, (long long)S_ * 3 * H_,
        qkv + H_, 3 * H_, (long long)S_ * 3 * H_,
        nullptr, sc, S_, (long long)S_ * S_, nullptr, S_, S_, H_, 0.03125f);

    // 4. softmax rows (in-place)
    softmax_rows<<<B_ * S_, 256, 0, stream>>>(sc, S_);

    // 5. out[b] = attn[b] @ vtb[b]^T  (fp32 out)
    dim3 g3(H_ / 128, S_ / 128, B_);
    gemm_bt<false, false, false><<<g3, 256, 0, stream>>>(
        sc,  S_, (long long)S_ * S_,
        vtb, S_, (long long)H_ * S_,
        nullptr, out, H_, (long long)S_ * H_, nullptr, S_, H_, S_, 1.0f);
}

// Round 6
// 260.642 us; speedup vs baseline: 1.2819x; 1.0116x over previous
//
#include <hip/hip_runtime.h>
#include <hip/hip_bf16.h>
#include <stdint.h>

#define B_ 4
#define S_ 2048
#define H_ 1024

typedef __attribute__((ext_vector_type(4))) float f32x4;
typedef __attribute__((ext_vector_type(8))) short bf16x8;

#define AS1C(p) ((const __attribute__((address_space(1))) void*)(p))
#define AS3(p)  ((__attribute__((address_space(3))) void*)(p))

// ------- one-shot prep: convert X, Wq|Wk|Wv, pack biases, zero rsum -------
__global__ __launch_bounds__(256)
void prep_k(const float* __restrict__ X,
            const float* __restrict__ Wq, const float* __restrict__ Wk,
            const float* __restrict__ Wv,
            const float* __restrict__ bq, const float* __restrict__ bk,
            const float* __restrict__ bv,
            __hip_bfloat16* __restrict__ Xb, __hip_bfloat16* __restrict__ Wall,
            float* __restrict__ ball, float* __restrict__ rsum)
{
    const int NX = B_ * S_ * H_ / 4;   // float4 count of X
    const int NW = H_ * H_ / 4;        // float4 count of one W
    int i = blockIdx.x * blockDim.x + threadIdx.x;
    if (i < NX + 3 * NW) {
        const float* src; uint64_t* dst; int li;
        if (i < NX) { src = X; dst = (uint64_t*)Xb; li = i; }
        else {
            int j = i - NX;
            int wsel = j / NW; li = j - wsel * NW;
            src = (wsel == 0) ? Wq : (wsel == 1) ? Wk : Wv;
            dst = (uint64_t*)Wall + (size_t)wsel * NW;
        }
        float4 v = ((const float4*)src)[li];
        union { __hip_bfloat16 h[4]; uint64_t u; } o;
        o.h[0] = __float2bfloat16(v.x);
        o.h[1] = __float2bfloat16(v.y);
        o.h[2] = __float2bfloat16(v.z);
        o.h[3] = __float2bfloat16(v.w);
        dst[li] = o.u;
    } else {
        int j = i - (NX + 3 * NW);
        if (j < 3 * H_ / 4) {                    // bias pack (float4)
            int bsel = j >> 8;
            int off  = j & 255;
            const float* src = (bsel == 0) ? bq : (bsel == 1) ? bk : bv;
            ((float4*)ball)[j] = ((const float4*)src)[off];
        } else if (j < 3 * H_ / 4 + B_ * S_ / 4) {   // zero rsum (float4)
            int j2 = j - 3 * H_ / 4;
            ((float4*)rsum)[j2] = make_float4(0.f, 0.f, 0.f, 0.f);
        }
    }
}

// ------- B-transposed bf16 GEMM, 16x16x32 MFMA, BK=64, single-buffer (r3) -------
// C[M,N] = scale * (A[M,K] @ B[N,K]^T) + bias[N]
// 128xBN block tile, 4 waves (2x2), wave tile 64 x BN/2.
// XOR chunk swizzle on staging+read: 0 LDS bank conflicts (r3-verified).
// V_SPLIT : blocks with bn>=2048 write transposed into vtrans[b][e][s].
// EXP_SUM : epilogue stores exp(scale*acc) bf16 and atomicAdds per-row sums to rsum.
// ROWDIV  : epilogue multiplies by 1/rsum[row] (fp32 out).
template<int BN, bool OUT_BF16, bool HAS_BIAS, bool V_SPLIT, bool EXP_SUM, bool ROWDIV>
__global__ __launch_bounds__(256)
void gemm_bt(const __hip_bfloat16* __restrict__ A, int lda, long long aBatch,
             const __hip_bfloat16* __restrict__ B, int ldb, long long bBatch,
             const float* __restrict__ bias,
             void* __restrict__ Cout, int ldc, long long cBatch,
             __hip_bfloat16* __restrict__ vtrans, float* __restrict__ rsum,
             int M, int N, int K, float scale)
{
    constexpr int FJ = BN / 32;        // B-frags per wave (16-col units)
    constexpr int SN = BN / 32;        // B staging steps (32 rows each)
    __shared__ __hip_bfloat16 lA[128 * 64];
    __shared__ __hip_bfloat16 lB[BN * 64];

    const int t  = threadIdx.x;
    const int bz = blockIdx.z;
    A += (long long)bz * aBatch;
    B += (long long)bz * bBatch;
    const int bm = blockIdx.y * 128;
    const int bn = blockIdx.x * BN;

    const int wave = t >> 6;
    const int lane = t & 63;
    const int wm = (wave & 1) * 64;
    const int wn = (wave >> 1) * (BN / 2);
    const int lm = lane & 15;
    const int kq = lane >> 4;
    const int cro = lm & 7;

    f32x4 acc[4][FJ] = {};

    const int srow = t >> 3;                         // 0..31
    const int swz  = ((t & 7) ^ ((t >> 3) & 7)) * 8;
    const __hip_bfloat16* gA = A + (long long)(bm + srow) * lda + swz;
    const __hip_bfloat16* gB = B + (long long)(bn + srow) * ldb + swz;
    __hip_bfloat16* sA = lA + t * 8;
    __hip_bfloat16* sB = lB + t * 8;

    for (int k0 = 0; k0 < K; k0 += 64) {
        __syncthreads();
#pragma unroll
        for (int s = 0; s < 4; ++s)
            __builtin_amdgcn_global_load_lds(AS1C(gA + (long long)s * 32 * lda + k0),
                                             AS3(sA + s * 2048), 16, 0, 0);
#pragma unroll
        for (int s = 0; s < SN; ++s)
            __builtin_amdgcn_global_load_lds(AS1C(gB + (long long)s * 32 * ldb + k0),
                                             AS3(sB + s * 2048), 16, 0, 0);
        __syncthreads();

#pragma unroll
        for (int ks = 0; ks < 2; ++ks) {
            bf16x8 af[4], bfr[FJ];
            const int ch = ((ks * 4 + kq) ^ cro) * 8;
#pragma unroll
            for (int i = 0; i < 4; ++i)
                af[i] = *(const bf16x8*)(lA + (wm + i * 16 + lm) * 64 + ch);
#pragma unroll
            for (int j = 0; j < FJ; ++j)
                bfr[j] = *(const bf16x8*)(lB + (wn + j * 16 + lm) * 64 + ch);
#pragma unroll
            for (int i = 0; i < 4; ++i)
#pragma unroll
                for (int j = 0; j < FJ; ++j)
                    acc[i][j] = __builtin_amdgcn_mfma_f32_16x16x32_bf16(af[i], bfr[j], acc[i][j], 0, 0, 0);
        }
    }

    // epilogue: C/D layout col = lane&15, row = (lane>>4)*4 + reg  [m89]
    const bool vmode = V_SPLIT && (bn >= 2 * H_);
    const int r0q = kq * 4;

    if (EXP_SUM) {
#pragma unroll
        for (int i = 0; i < 4; ++i) {
            const int rowb = bm + wm + i * 16 + r0q;
            float ps[4] = {0.f, 0.f, 0.f, 0.f};
#pragma unroll
            for (int j = 0; j < FJ; ++j) {
                const int col = bn + wn + j * 16 + lm;
#pragma unroll
                for (int r = 0; r < 4; ++r) {
                    float e = __expf(acc[i][j][r] * scale);
                    ps[r] += e;
                    ((__hip_bfloat16*)Cout)[(long long)bz * cBatch +
                        (long long)(rowb + r) * ldc + col] = __float2bfloat16(e);
                }
            }
#pragma unroll
            for (int r = 0; r < 4; ++r) {
#pragma unroll
                for (int m = 1; m < 16; m <<= 1)
                    ps[r] += __shfl_xor(ps[r], m);
            }
            if (lm == 0) {
#pragma unroll
                for (int r = 0; r < 4; ++r)
                    atomicAdd(rsum + bz * S_ + rowb + r, ps[r]);
            }
        }
        return;
    }

#pragma unroll
    for (int i = 0; i < 4; ++i) {
        const int rowb = bm + wm + i * 16 + r0q;
        float inv[4];
        if (ROWDIV) {
            float4 rs = *(const float4*)(rsum + bz * S_ + rowb);
            inv[0] = 1.0f / rs.x; inv[1] = 1.0f / rs.y;
            inv[2] = 1.0f / rs.z; inv[3] = 1.0f / rs.w;
        }
#pragma unroll
        for (int j = 0; j < FJ; ++j) {
            const int col = bn + wn + j * 16 + lm;
            float bvv = 0.0f;
            if (HAS_BIAS) bvv = bias[col];
            if (!vmode) {
#pragma unroll
                for (int r = 0; r < 4; ++r) {
                    float val = ROWDIV ? acc[i][j][r] * inv[r]
                                       : acc[i][j][r] * scale + bvv;
                    long long idx = (long long)bz * cBatch + (long long)(rowb + r) * ldc + col;
                    if (OUT_BF16) ((__hip_bfloat16*)Cout)[idx] = __float2bfloat16(val);
                    else          ((float*)Cout)[idx] = val;
                }
            } else {
                // vtrans[b][e][s]: b = rowb>>11, s = rowb&2047 (+r contiguous), e = col-2048
                const long long ebase = (long long)((rowb >> 11) * H_ + col - 2 * H_) * S_;
                union { ushort4 u; __hip_bfloat16 h[4]; } o;
#pragma unroll
                for (int r = 0; r < 4; ++r)
                    o.h[r] = __float2bfloat16(acc[i][j][r] + bvv);
                *(ushort4*)(vtrans + ebase + (rowb & 2047)) = o.u;
            }
        }
    }
}

// ---------------- launcher ----------------
extern "C" void kernel_launch(void* const* d_in, const int* in_sizes, int n_in,
                              void* d_out, int out_size, void* d_ws, size_t ws_size,
                              hipStream_t stream)
{
    const float* X  = (const float*)d_in[0];
    const float* Wq = (const float*)d_in[1];
    const float* bq = (const float*)d_in[2];
    const float* Wk = (const float*)d_in[3];
    const float* bk = (const float*)d_in[4];
    const float* Wv = (const float*)d_in[5];
    const float* bv = (const float*)d_in[6];
    float* out = (float*)d_out;

    char* w = (char*)d_ws;
    const size_t MB = 1ull << 20;
    // Layout (~80 MB):
    //   [0,16)   Xb          (dead after QKV gemm)
    //   [16,22)  Wall bf16 [3072,1024]   (dead after QKV gemm)
    //   [22,23)  ball fp32 [3072]        (dead after QKV gemm)
    //   [0,32)   sc  exp-scores bf16 [B,S,S]   (overlays dead Xb/Wall/ball)
    //   [32,64)  qk  bf16 [8192,2048]  (Q cols 0..1023, K cols 1024..2047)
    //   [64,80)  vtb bf16 [B,H,S]  (written transposed by QKV epilogue)
    //   [80MB, +32KB) rsum fp32 [B*S]
    __hip_bfloat16* Xb   = (__hip_bfloat16*)(w + 0);
    __hip_bfloat16* Wall = (__hip_bfloat16*)(w + 16 * MB);
    float*          ball = (float*)        (w + 22 * MB);
    __hip_bfloat16* sc   = (__hip_bfloat16*)(w + 0);
    __hip_bfloat16* qk   = (__hip_bfloat16*)(w + 32 * MB);
    __hip_bfloat16* vtb  = (__hip_bfloat16*)(w + 64 * MB);
    float*          rsum = (float*)        (w + 80 * MB);

    // 1. prep (X/W convert + bias pack + rsum zero)
    const int prep_items = B_ * S_ * H_ / 4 + 3 * H_ * H_ / 4 + 3 * H_ / 4 + B_ * S_ / 4;
    prep_k<<<(prep_items + 255) / 256, 256, 0, stream>>>(X, Wq, Wk, Wv, bq, bk, bv,
                                                         Xb, Wall, ball, rsum);

    // 2. fused QKV projection; Q,K -> qk (ldc=2048), V blocks -> vtb transposed
    dim3 g1(3 * H_ / 128, (B_ * S_) / 128, 1);
    gemm_bt<128, true, true, true, false, false><<<g1, 256, 0, stream>>>(
        Xb, H_, 0, Wall, H_, 0, ball, qk, 2 * H_, 0, vtb, nullptr,
        B_ * S_, 3 * H_, H_, 1.0f);

    // 3. exp-scores[b] = exp((q[b] @ k[b]^T)/32), bf16 + row sums into rsum
    dim3 g2(S_ / 128, S_ / 128, B_);
    gemm_bt<128, true, false, false, true, false><<<g2, 256, 0, stream>>>(
        qk,      2 * H_, (long long)S_ * 2 * H_,
        qk + H_, 2 * H_, (long long)S_ * 2 * H_,
        nullptr, sc, S_, (long long)S_ * S_, nullptr, rsum, S_, S_, H_, 0.03125f);

    // 4. out[b] = (exp-scores[b] @ vtb[b]^T) / rsum  (fp32 out, 128x64 tiles)
    dim3 g3(H_ / 64, S_ / 128, B_);
    gemm_bt<64, false, false, false, false, true><<<g3, 256, 0, stream>>>(
        sc,  S_, (long long)S_ * S_,
        vtb, S_, (long long)H_ * S_,
        nullptr, out, H_, (long long)S_ * H_, nullptr, rsum, S_, H_, S_, 1.0f);
}

// Round 7
// 253.384 us; speedup vs baseline: 1.3187x; 1.0286x over previous
//
#include <hip/hip_runtime.h>
#include <hip/hip_bf16.h>
#include <stdint.h>

#define B_ 4
#define S_ 2048
#define H_ 1024

typedef __attribute__((ext_vector_type(4))) float f32x4;
typedef __attribute__((ext_vector_type(8))) short bf16x8;

#define AS1C(p) ((const __attribute__((address_space(1))) void*)(p))
#define AS3(p)  ((__attribute__((address_space(3))) void*)(p))

// ------- one-shot prep: convert X, Wq|Wk|Wv, pack biases, zero rsum -------
__global__ __launch_bounds__(256)
void prep_k(const float* __restrict__ X,
            const float* __restrict__ Wq, const float* __restrict__ Wk,
            const float* __restrict__ Wv,
            const float* __restrict__ bq, const float* __restrict__ bk,
            const float* __restrict__ bv,
            __hip_bfloat16* __restrict__ Xb, __hip_bfloat16* __restrict__ Wall,
            float* __restrict__ ball, float* __restrict__ rsum)
{
    const int NX = B_ * S_ * H_ / 4;   // float4 count of X
    const int NW = H_ * H_ / 4;        // float4 count of one W (2^18)
    int i = blockIdx.x * blockDim.x + threadIdx.x;
    if (i < NX + 3 * NW) {
        const float* src; uint64_t* dst; int li;
        if (i < NX) { src = X; dst = (uint64_t*)Xb; li = i; }
        else {
            int j = i - NX;
            int wsel = j / NW; li = j - wsel * NW;
            src = (wsel == 0) ? Wq : (wsel == 1) ? Wk : Wv;
            dst = (uint64_t*)Wall + (size_t)wsel * NW;
        }
        float4 v = ((const float4*)src)[li];
        union { __hip_bfloat16 h[4]; uint64_t u; } o;
        o.h[0] = __float2bfloat16(v.x);
        o.h[1] = __float2bfloat16(v.y);
        o.h[2] = __float2bfloat16(v.z);
        o.h[3] = __float2bfloat16(v.w);
        dst[li] = o.u;
    } else {
        int j = i - (NX + 3 * NW);
        if (j < 3 * H_ / 4) {                    // bias pack (float4)
            int bsel = j >> 8;
            int off  = j & 255;
            const float* src = (bsel == 0) ? bq : (bsel == 1) ? bk : bv;
            ((float4*)ball)[j] = ((const float4*)src)[off];
        } else if (j < 3 * H_ / 4 + B_ * S_ / 4) {   // zero rsum (float4)
            int j2 = j - 3 * H_ / 4;
            ((float4*)rsum)[j2] = make_float4(0.f, 0.f, 0.f, 0.f);
        }
    }
}

// ------- B-transposed bf16 GEMM, 16x16x32 MFMA, BK=64, single-buffer -------
// C[M,N] = scale * (A[M,K] @ B[N,K]^T) + bias[N]
// 128xBN block tile, 4 waves (2x2), wave tile 64 x BN/2.
// XOR chunk swizzle on staging+read: 0 LDS bank conflicts (r3-verified).
// MINW: __launch_bounds__ min-waves/EU — 4 forces <=128 regs -> 4 blocks/CU,
//       used on the 1024-block dispatches (scores/PV) so grid = exactly 1 round.
// V_SPLIT : blocks with bn>=2048 write transposed into vtrans[b][e][s].
// EXP_SUM : epilogue stores exp(scale*acc) bf16 and atomicAdds per-row sums to rsum.
// ROWDIV  : epilogue multiplies by 1/rsum[row] (fp32 out).
template<int BN, int MINW, bool OUT_BF16, bool HAS_BIAS, bool V_SPLIT, bool EXP_SUM, bool ROWDIV>
__global__ __launch_bounds__(256, MINW)
void gemm_bt(const __hip_bfloat16* __restrict__ A, int lda, long long aBatch,
             const __hip_bfloat16* __restrict__ B, int ldb, long long bBatch,
             const float* __restrict__ bias,
             void* __restrict__ Cout, int ldc, long long cBatch,
             __hip_bfloat16* __restrict__ vtrans, float* __restrict__ rsum,
             int M, int N, int K, float scale)
{
    constexpr int FJ = BN / 32;        // B-frags per wave (16-col units)
    constexpr int SN = BN / 32;        // B staging steps (32 rows each)
    __shared__ __hip_bfloat16 lA[128 * 64];
    __shared__ __hip_bfloat16 lB[BN * 64];

    const int t  = threadIdx.x;
    const int bz = blockIdx.z;
    A += (long long)bz * aBatch;
    B += (long long)bz * bBatch;
    const int bm = blockIdx.y * 128;
    const int bn = blockIdx.x * BN;

    const int wave = t >> 6;
    const int lane = t & 63;
    const int wm = (wave & 1) * 64;
    const int wn = (wave >> 1) * (BN / 2);
    const int lm = lane & 15;
    const int kq = lane >> 4;
    const int cro = lm & 7;

    f32x4 acc[4][FJ] = {};

    const int srow = t >> 3;                         // 0..31
    const int swz  = ((t & 7) ^ ((t >> 3) & 7)) * 8;
    const __hip_bfloat16* gA = A + (long long)(bm + srow) * lda + swz;
    const __hip_bfloat16* gB = B + (long long)(bn + srow) * ldb + swz;
    __hip_bfloat16* sA = lA + t * 8;
    __hip_bfloat16* sB = lB + t * 8;

    for (int k0 = 0; k0 < K; k0 += 64) {
        __syncthreads();
#pragma unroll
        for (int s = 0; s < 4; ++s)
            __builtin_amdgcn_global_load_lds(AS1C(gA + (long long)s * 32 * lda + k0),
                                             AS3(sA + s * 2048), 16, 0, 0);
#pragma unroll
        for (int s = 0; s < SN; ++s)
            __builtin_amdgcn_global_load_lds(AS1C(gB + (long long)s * 32 * ldb + k0),
                                             AS3(sB + s * 2048), 16, 0, 0);
        __syncthreads();

#pragma unroll
        for (int ks = 0; ks < 2; ++ks) {
            bf16x8 af[4], bfr[FJ];
            const int ch = ((ks * 4 + kq) ^ cro) * 8;
#pragma unroll
            for (int i = 0; i < 4; ++i)
                af[i] = *(const bf16x8*)(lA + (wm + i * 16 + lm) * 64 + ch);
#pragma unroll
            for (int j = 0; j < FJ; ++j)
                bfr[j] = *(const bf16x8*)(lB + (wn + j * 16 + lm) * 64 + ch);
#pragma unroll
            for (int i = 0; i < 4; ++i)
#pragma unroll
                for (int j = 0; j < FJ; ++j)
                    acc[i][j] = __builtin_amdgcn_mfma_f32_16x16x32_bf16(af[i], bfr[j], acc[i][j], 0, 0, 0);
        }
    }

    // epilogue: C/D layout col = lane&15, row = (lane>>4)*4 + reg  [m89]
    const bool vmode = V_SPLIT && (bn >= 2 * H_);
    const int r0q = kq * 4;

    if (EXP_SUM) {
#pragma unroll
        for (int i = 0; i < 4; ++i) {
            const int rowb = bm + wm + i * 16 + r0q;
            float ps[4] = {0.f, 0.f, 0.f, 0.f};
#pragma unroll
            for (int j = 0; j < FJ; ++j) {
                const int col = bn + wn + j * 16 + lm;
#pragma unroll
                for (int r = 0; r < 4; ++r) {
                    float e = __expf(acc[i][j][r] * scale);
                    ps[r] += e;
                    ((__hip_bfloat16*)Cout)[(long long)bz * cBatch +
                        (long long)(rowb + r) * ldc + col] = __float2bfloat16(e);
                }
            }
#pragma unroll
            for (int r = 0; r < 4; ++r) {
#pragma unroll
                for (int m = 1; m < 16; m <<= 1)
                    ps[r] += __shfl_xor(ps[r], m);
            }
            if (lm == 0) {
#pragma unroll
                for (int r = 0; r < 4; ++r)
                    atomicAdd(rsum + bz * S_ + rowb + r, ps[r]);
            }
        }
        return;
    }

#pragma unroll
    for (int i = 0; i < 4; ++i) {
        const int rowb = bm + wm + i * 16 + r0q;
        float inv[4];
        if (ROWDIV) {
            float4 rs = *(const float4*)(rsum + bz * S_ + rowb);
            inv[0] = 1.0f / rs.x; inv[1] = 1.0f / rs.y;
            inv[2] = 1.0f / rs.z; inv[3] = 1.0f / rs.w;
        }
#pragma unroll
        for (int j = 0; j < FJ; ++j) {
            const int col = bn + wn + j * 16 + lm;
            float bvv = 0.0f;
            if (HAS_BIAS) bvv = bias[col];
            if (!vmode) {
#pragma unroll
                for (int r = 0; r < 4; ++r) {
                    float val = ROWDIV ? acc[i][j][r] * inv[r]
                                       : acc[i][j][r] * scale + bvv;
                    long long idx = (long long)bz * cBatch + (long long)(rowb + r) * ldc + col;
                    if (OUT_BF16) ((__hip_bfloat16*)Cout)[idx] = __float2bfloat16(val);
                    else          ((float*)Cout)[idx] = val;
                }
            } else {
                // vtrans[b][e][s]: b = rowb>>11, s = rowb&2047 (+r contiguous), e = col-2048
                const long long ebase = (long long)((rowb >> 11) * H_ + col - 2 * H_) * S_;
                union { ushort4 u; __hip_bfloat16 h[4]; } o;
#pragma unroll
                for (int r = 0; r < 4; ++r)
                    o.h[r] = __float2bfloat16(acc[i][j][r] + bvv);
                *(ushort4*)(vtrans + ebase + (rowb & 2047)) = o.u;
            }
        }
    }
}

// ---------------- launcher ----------------
extern "C" void kernel_launch(void* const* d_in, const int* in_sizes, int n_in,
                              void* d_out, int out_size, void* d_ws, size_t ws_size,
                              hipStream_t stream)
{
    const float* X  = (const float*)d_in[0];
    const float* Wq = (const float*)d_in[1];
    const float* bq = (const float*)d_in[2];
    const float* Wk = (const float*)d_in[3];
    const float* bk = (const float*)d_in[4];
    const float* Wv = (const float*)d_in[5];
    const float* bv = (const float*)d_in[6];
    float* out = (float*)d_out;

    char* w = (char*)d_ws;
    const size_t MB = 1ull << 20;
    // Layout (~80 MB):
    //   [0,16)   Xb          (dead after QKV gemm)
    //   [16,22)  Wall bf16 [3072,1024]   (dead after QKV gemm)
    //   [22,23)  ball fp32 [3072]        (dead after QKV gemm)
    //   [0,32)   sc  exp-scores bf16 [B,S,S]   (overlays dead Xb/Wall/ball)
    //   [32,64)  qk  bf16 [8192,2048]  (Q cols 0..1023, K cols 1024..2047)
    //   [64,80)  vtb bf16 [B,H,S]  (written transposed by QKV epilogue)
    //   [80MB, +32KB) rsum fp32 [B*S]
    __hip_bfloat16* Xb   = (__hip_bfloat16*)(w + 0);
    __hip_bfloat16* Wall = (__hip_bfloat16*)(w + 16 * MB);
    float*          ball = (float*)        (w + 22 * MB);
    __hip_bfloat16* sc   = (__hip_bfloat16*)(w + 0);
    __hip_bfloat16* qk   = (__hip_bfloat16*)(w + 32 * MB);
    __hip_bfloat16* vtb  = (__hip_bfloat16*)(w + 64 * MB);
    float*          rsum = (float*)        (w + 80 * MB);

    // 1. prep (X/W convert + bias pack + rsum zero)
    const int prep_items = B_ * S_ * H_ / 4 + 3 * H_ * H_ / 4 + 3 * H_ / 4 + B_ * S_ / 4;
    prep_k<<<(prep_items + 255) / 256, 256, 0, stream>>>(X, Wq, Wk, Wv, bq, bk, bv,
                                                         Xb, Wall, ball, rsum);

    // 2. fused QKV projection (1536 blocks = 2 exact rounds @3/CU — leave bounds alone)
    dim3 g1(3 * H_ / 128, (B_ * S_) / 128, 1);
    gemm_bt<128, 1, true, true, true, false, false><<<g1, 256, 0, stream>>>(
        Xb, H_, 0, Wall, H_, 0, ball, qk, 2 * H_, 0, vtb, nullptr,
        B_ * S_, 3 * H_, H_, 1.0f);

    // 3. exp-scores (1024 blocks; MINW=4 -> 4 blocks/CU -> exactly 1 round)
    dim3 g2(S_ / 128, S_ / 128, B_);
    gemm_bt<128, 4, true, false, false, true, false><<<g2, 256, 0, stream>>>(
        qk,      2 * H_, (long long)S_ * 2 * H_,
        qk + H_, 2 * H_, (long long)S_ * 2 * H_,
        nullptr, sc, S_, (long long)S_ * S_, nullptr, rsum, S_, S_, H_, 0.03125f);

    // 4. out[b] = (exp-scores[b] @ vtb[b]^T) / rsum  (1024 blocks; MINW=4)
    dim3 g3(H_ / 64, S_ / 128, B_);
    gemm_bt<64, 4, false, false, false, false, true><<<g3, 256, 0, stream>>>(
        sc,  S_, (long long)S_ * S_,
        vtb, S_, (long long)H_ * S_,
        nullptr, out, H_, (long long)S_ * H_, nullptr, rsum, S_, H_, S_, 1.0f);
}